// Round 2
// baseline (421.478 us; speedup 1.0000x reference)
//
#include <hip/hip_runtime.h>
#include <hip/hip_bf16.h>
#include <math.h>

typedef unsigned short u16;
typedef unsigned int   u32;
typedef __bf16 bf16x8 __attribute__((ext_vector_type(8)));
typedef float  f32x4  __attribute__((ext_vector_type(4)));

#define NRAYS 262144
#define NBLK  (NRAYS / 64)

// Packed-weight layer offsets (in u16 elements) = chunk_start * 512
enum : int { PO0=0, PO1=16384, PO2=81920, PO3=147456, PO4=212992,
             PO5=294912, PO6=360448, PO7=425984, PO8=491520, PO9=528384 };
#define TOTAL_PACK_ELEMS 530432   // = 1036 chunks * 512

__device__ __forceinline__ u16 f2bf(float x) {
  return (u16)((__float_as_uint(x) + 0x8000u) >> 16);   // round-half-up
}

// ---------------------------------------------------------------------------
// Weight pack kernel (unchanged layout): fp32 W[K][N] -> bf16 A-fragment order
// chunk = kstep*MT + mtile; [lane][j] = W[k = kstep*32+(lane>>4)*8+j][m = mtile*16+(lane&15)]
// ---------------------------------------------------------------------------
struct PackArgs {
  const float* src[10];
  int K[10]; int N[10]; int l2mt[10]; int cstart[11];
};

__global__ __launch_bounds__(256) void pack_w(PackArgs a, u16* __restrict__ dst)
{
  int e = blockIdx.x * 256 + threadIdx.x;
  if (e >= TOTAL_PACK_ELEMS) return;
  int chunk = e >> 9;
  int li = 0;
  #pragma unroll
  for (int t = 1; t < 10; ++t) li += (chunk >= a.cstart[t]) ? 1 : 0;
  int lc = chunk - a.cstart[li];
  int ks = lc >> a.l2mt[li];
  int mt = lc - (ks << a.l2mt[li]);
  int lane = (e >> 3) & 63, j = e & 7;
  int k = ks * 32 + ((lane >> 4) << 3) + j;
  int n = mt * 16 + (lane & 15);
  float v = 0.f;
  if (k < a.K[li] && n < a.N[li]) v = a.src[li][(size_t)k * a.N[li] + n];
  // RNE here (weights packed once, keep best precision)
  u32 u = __float_as_uint(v);
  dst[e] = (u16)((u + 0x7FFFu + ((u >> 16) & 1u)) >> 16);
}

// ---------------------------------------------------------------------------
// Fused NeRF: 64 rays/block, 4 waves. Single 64x320 swizzled LDS buffer:
//   cols 0..255 = z, cols 256..319 = pe (persists to L4), de overlaid at
//   288..319 after L4. Element (r,c) at u16 addr r*320 + ((c>>3)^(r&7))*8 + (c&7).
// ---------------------------------------------------------------------------
__device__ __forceinline__ void wr_enc(u16* zb, int r, int c, u16 v) {
  zb[r * 320 + ((((c >> 3) ^ (r & 7))) << 3) + (c & 7)] = v;
}

template<int MT_W>
__device__ __forceinline__ void binit(f32x4 acc[MT_W][4],
    const float* __restrict__ bias, int chbase, int lane)
{
  const int q = lane >> 4;
  #pragma unroll
  for (int mt = 0; mt < MT_W; ++mt) {
    float4 bv = *(const float4*)(bias + chbase + mt * 16 + q * 4);
    #pragma unroll
    for (int nt = 0; nt < 4; ++nt)
      acc[mt][nt] = (f32x4){bv.x, bv.y, bv.z, bv.w};
  }
}

// B from swizzled LDS (cbase8 = starting 8-col chunk), A from packed global.
template<int MT_W, int NSTEPS, int MT_TOTAL>
__device__ __forceinline__ void gseg(f32x4 acc[MT_W][4],
    const u16* __restrict__ zb, int cbase8,
    const u16* __restrict__ wl, int mt0, int ksbase, int lane)
{
  const int q = lane >> 4, llo = lane & 15;
  #pragma unroll
  for (int ks = 0; ks < NSTEPS; ++ks) {
    int c8s = ((cbase8 + ks * 4 + q) ^ (llo & 7));
    const u16* bp = zb + llo * 320 + c8s * 8;
    bf16x8 b[4];
    #pragma unroll
    for (int nt = 0; nt < 4; ++nt)
      b[nt] = *(const bf16x8*)(bp + nt * 16 * 320);
    int widx = ((ksbase + ks) * MT_TOTAL + mt0) * 512 + lane * 8;
    bf16x8 a[MT_W];
    #pragma unroll
    for (int mt = 0; mt < MT_W; ++mt)
      a[mt] = *(const bf16x8*)(wl + widx + mt * 512);
    #pragma unroll
    for (int mt = 0; mt < MT_W; ++mt)
      #pragma unroll
      for (int nt = 0; nt < 4; ++nt)
        acc[mt][nt] = __builtin_amdgcn_mfma_f32_16x16x32_bf16(a[mt], b[nt], acc[mt][nt], 0, 0, 0);
  }
}

template<int MT_W, bool RELU>
__device__ __forceinline__ void zstore(f32x4 acc[MT_W][4],
    int chbase, u16* zb, int lane)
{
  const int llo = lane & 15, q = lane >> 4;
  #pragma unroll
  for (int mt = 0; mt < MT_W; ++mt) {
    int ch = chbase + mt * 16 + q * 4;          // 4 consecutive out-channels
    int off0 = (((ch >> 3) ^ (llo & 7)) << 3) + (ch & 7);
    #pragma unroll
    for (int nt = 0; nt < 4; ++nt) {
      f32x4 v = acc[mt][nt];
      float x0 = v.x, x1 = v.y, x2 = v.z, x3 = v.w;
      if (RELU) { x0 = fmaxf(x0, 0.f); x1 = fmaxf(x1, 0.f);
                  x2 = fmaxf(x2, 0.f); x3 = fmaxf(x3, 0.f); }
      u32 a0 = __float_as_uint(x0) + 0x8000u;
      u32 a1 = __float_as_uint(x1) + 0x8000u;
      u32 a2 = __float_as_uint(x2) + 0x8000u;
      u32 a3 = __float_as_uint(x3) + 0x8000u;
      uint2 pk;
      pk.x = (a1 & 0xFFFF0000u) | (a0 >> 16);
      pk.y = (a3 & 0xFFFF0000u) | (a2 >> 16);
      *(uint2*)(zb + (nt * 16 + llo) * 320 + off0) = pk;
    }
  }
}

__global__ __launch_bounds__(256, 4) void nerf_fused(
    const float* __restrict__ pos,  const float* __restrict__ dirv,
    const float* __restrict__ b00,  const float* __restrict__ b01,
    const float* __restrict__ b02,  const float* __restrict__ b03,
    const float* __restrict__ b10,  const float* __restrict__ b11,
    const float* __restrict__ b12,  const float* __restrict__ b13,
    const float* __restrict__ cb0,  const float* __restrict__ cb1,
    const u16* __restrict__ W, float* __restrict__ out)
{
  __shared__ __align__(16) u16 zb[64 * 320];   // 40960 B -> 4 blocks/CU
  float* xyzf = (float*)zb;                    // pos scratch in z-region (dead until L0 store)

  const int tid = threadIdx.x;
  const int rb  = blockIdx.x * 64;
  const int lane = tid & 63, wid = tid >> 6;

  if (tid < 192) {
    int r = tid / 3, c = tid - r * 3;
    xyzf[r * 160 + c] = pos[(size_t)(rb + r) * 3 + c];   // byte r*640+4c: no pe overlap
  }
  __syncthreads();

  // pe encode -> zb cols 256..319: [x0..x2, sin(t=j*10+l) t<30, cos, 0]
  #pragma unroll
  for (int i = tid; i < 64 * 32; i += 256) {
    int r = i >> 5, t = i & 31;
    if (t < 30) {
      int j = t / 10, l = t - j * 10;
      float x = xyzf[r * 160 + j] * (float)(1 << l);
      wr_enc(zb, r, 256 + 3 + t,  f2bf(__sinf(x)));
      wr_enc(zb, r, 256 + 33 + t, f2bf(__cosf(x)));
    }
  }
  {
    int r = tid >> 2, c = tid & 3;
    u16 v = 0; int col = 63;
    if (c < 3) { col = c; v = f2bf(xyzf[r * 160 + c]); }
    wr_enc(zb, r, 256 + col, v);
  }
  __syncthreads();

  f32x4 acc[4][4];

  // L0: pe(64) -> 256
  binit<4>(acc, b00, wid * 64, lane);
  gseg<4, 2, 16>(acc, zb, 32, W + PO0, wid * 4, 0, lane);
  __syncthreads();
  zstore<4, true>(acc, wid * 64, zb, lane);
  __syncthreads();
  // L1..L3: 256 -> 256
  binit<4>(acc, b01, wid * 64, lane);
  gseg<4, 8, 16>(acc, zb, 0, W + PO1, wid * 4, 0, lane);
  __syncthreads();
  zstore<4, true>(acc, wid * 64, zb, lane);
  __syncthreads();
  binit<4>(acc, b02, wid * 64, lane);
  gseg<4, 8, 16>(acc, zb, 0, W + PO2, wid * 4, 0, lane);
  __syncthreads();
  zstore<4, true>(acc, wid * 64, zb, lane);
  __syncthreads();
  binit<4>(acc, b03, wid * 64, lane);
  gseg<4, 8, 16>(acc, zb, 0, W + PO3, wid * 4, 0, lane);
  __syncthreads();
  zstore<4, true>(acc, wid * 64, zb, lane);
  __syncthreads();
  // L4: concat(z, pe) 319 -> 256
  binit<4>(acc, b10, wid * 64, lane);
  gseg<4, 8, 16>(acc, zb, 0,  W + PO4, wid * 4, 0, lane);
  gseg<4, 2, 16>(acc, zb, 32, W + PO4, wid * 4, 8, lane);
  __syncthreads();
  zstore<4, true>(acc, wid * 64, zb, lane);
  // de encode -> zb cols 288..319 (pe cols 32..63 dead after L4)
  #pragma unroll
  for (int i = tid; i < 64 * 16; i += 256) {
    int r = i >> 4, t = i & 15;
    if (t < 12) {
      int j = t >> 2, l = t & 3;
      float x = dirv[(size_t)(rb + r) * 3 + j] * (float)(1 << l);
      wr_enc(zb, r, 288 + 3 + t,  f2bf(__sinf(x)));
      wr_enc(zb, r, 288 + 15 + t, f2bf(__cosf(x)));
    } else {
      wr_enc(zb, r, 288 + 15 + t, 0);   // cols 27..30 zero
    }
  }
  {
    int r = tid >> 2, c = tid & 3;
    u16 v = 0; int col = 31;
    if (c < 3) { col = c; v = f2bf(dirv[(size_t)(rb + r) * 3 + c]); }
    wr_enc(zb, r, 288 + col, v);
  }
  __syncthreads();
  // L5, L6: 256 -> 256 relu
  binit<4>(acc, b11, wid * 64, lane);
  gseg<4, 8, 16>(acc, zb, 0, W + PO5, wid * 4, 0, lane);
  __syncthreads();
  zstore<4, true>(acc, wid * 64, zb, lane);
  __syncthreads();
  binit<4>(acc, b12, wid * 64, lane);
  gseg<4, 8, 16>(acc, zb, 0, W + PO6, wid * 4, 0, lane);
  __syncthreads();
  zstore<4, true>(acc, wid * 64, zb, lane);
  __syncthreads();
  // L7: 256 -> 256, NO relu
  binit<4>(acc, b13, wid * 64, lane);
  gseg<4, 8, 16>(acc, zb, 0, W + PO7, wid * 4, 0, lane);
  __syncthreads();
  zstore<4, false>(acc, wid * 64, zb, lane);
  __syncthreads();
  // L8: concat(z, de) 283 -> 128 relu
  {
    f32x4 acc2[2][4];
    binit<2>(acc2, cb0, wid * 32, lane);
    gseg<2, 8, 8>(acc2, zb, 0,  W + PO8, wid * 2, 0, lane);
    gseg<2, 1, 8>(acc2, zb, 36, W + PO8, wid * 2, 8, lane);
    __syncthreads();
    zstore<2, true>(acc2, wid * 32, zb, lane);
    __syncthreads();
  }
  // L9: 128 -> 4 + nonlinearities. One wave handles its 16 rays.
  {
    const u16* W9 = W + PO9;
    const int q = lane >> 4, llo = lane & 15;
    const int r = wid * 16 + llo;
    f32x4 c9 = (f32x4){0.f, 0.f, 0.f, 0.f};
    #pragma unroll
    for (int ks = 0; ks < 4; ++ks) {
      int c8s = ((ks * 4 + q) ^ (llo & 7));
      bf16x8 b = *(const bf16x8*)(zb + r * 320 + c8s * 8);
      bf16x8 a = *(const bf16x8*)(W9 + ks * 512 + lane * 8);
      c9 = __builtin_amdgcn_mfma_f32_16x16x32_bf16(a, b, c9, 0, 0, 0);
    }
    if (q == 0) {
      int ray = rb + r;
      float o0 = c9.x + cb1[0];
      float o1 = c9.y + cb1[1];
      float o2 = c9.z + cb1[2];
      float dv = c9.w + cb1[3];
      out[ray] = (dv > 8.f) ? dv : log1pf(__expf(dv));
      float* rgb = out + NRAYS + (size_t)ray * 3;
      rgb[0] = 1.f / (1.f + __expf(-o0));
      rgb[1] = 1.f / (1.f + __expf(-o1));
      rgb[2] = 1.f / (1.f + __expf(-o2));
    }
  }
}

// ---------------------------------------------------------------------------
extern "C" void kernel_launch(void* const* d_in, const int* in_sizes, int n_in,
                              void* d_out, int out_size, void* d_ws, size_t ws_size,
                              hipStream_t stream)
{
  (void)in_sizes; (void)n_in; (void)out_size; (void)ws_size;
  const float* pos  = (const float*)d_in[0];
  const float* dirv = (const float*)d_in[1];
  PackArgs pa;
  const int widx[10] = {5, 7, 9, 11, 13, 15, 17, 19, 21, 23};
  const int K[10]    = {63, 256, 256, 256, 319, 256, 256, 256, 283, 128};
  const int Nn[10]   = {256, 256, 256, 256, 256, 256, 256, 256, 128, 4};
  const int L2MT[10] = {4, 4, 4, 4, 4, 4, 4, 4, 3, 0};
  const int CS[11]   = {0, 32, 160, 288, 416, 576, 704, 832, 960, 1032, 1036};
  for (int i = 0; i < 10; ++i) {
    pa.src[i] = (const float*)d_in[widx[i]];
    pa.K[i] = K[i]; pa.N[i] = Nn[i]; pa.l2mt[i] = L2MT[i];
  }
  for (int i = 0; i < 11; ++i) pa.cstart[i] = CS[i];

  u16* wp = (u16*)d_ws;
  hipLaunchKernelGGL(pack_w, dim3(TOTAL_PACK_ELEMS / 256), dim3(256), 0, stream, pa, wp);

  hipLaunchKernelGGL(nerf_fused, dim3(NBLK), dim3(256), 0, stream,
      pos, dirv,
      (const float*)d_in[6],  (const float*)d_in[8],
      (const float*)d_in[10], (const float*)d_in[12],
      (const float*)d_in[14], (const float*)d_in[16],
      (const float*)d_in[18], (const float*)d_in[20],
      (const float*)d_in[22], (const float*)d_in[24],
      wp, (float*)d_out);
}

// Round 3
// 354.684 us; speedup vs baseline: 1.1883x; 1.1883x over previous
//
#include <hip/hip_runtime.h>
#include <hip/hip_bf16.h>
#include <math.h>

typedef unsigned short u16;
typedef unsigned int   u32;
typedef __bf16 bf16x8 __attribute__((ext_vector_type(8)));
typedef float  f32x4  __attribute__((ext_vector_type(4)));

#define NRAYS 262144
#define NBLK  (NRAYS / 64)

// Packed-weight layer offsets (in u16 elements) = chunk_start * 512
enum : int { PO0=0, PO1=16384, PO2=81920, PO3=147456, PO4=212992,
             PO5=294912, PO6=360448, PO7=425984, PO8=491520, PO9=528384 };
#define TOTAL_PACK_ELEMS 530432   // = 1036 chunks * 512

__device__ __forceinline__ u16 f2bf(float x) {
  return (u16)((__float_as_uint(x) + 0x8000u) >> 16);   // round-half-up
}

// ---------------------------------------------------------------------------
// Weight pack kernel: fp32 W[K][N] -> bf16 A-fragment order
// chunk = kstep*MT + mtile; [lane][j] = W[k = kstep*32+(lane>>4)*8+j][m = mtile*16+(lane&15)]
// ---------------------------------------------------------------------------
struct PackArgs {
  const float* src[10];
  int K[10]; int N[10]; int l2mt[10]; int cstart[11];
};

__global__ __launch_bounds__(256) void pack_w(PackArgs a, u16* __restrict__ dst)
{
  int e = blockIdx.x * 256 + threadIdx.x;
  if (e >= TOTAL_PACK_ELEMS) return;
  int chunk = e >> 9;
  int li = 0;
  #pragma unroll
  for (int t = 1; t < 10; ++t) li += (chunk >= a.cstart[t]) ? 1 : 0;
  int lc = chunk - a.cstart[li];
  int ks = lc >> a.l2mt[li];
  int mt = lc - (ks << a.l2mt[li]);
  int lane = (e >> 3) & 63, j = e & 7;
  int k = ks * 32 + ((lane >> 4) << 3) + j;
  int n = mt * 16 + (lane & 15);
  float v = 0.f;
  if (k < a.K[li] && n < a.N[li]) v = a.src[li][(size_t)k * a.N[li] + n];
  // RNE here (weights packed once, keep best precision)
  u32 u = __float_as_uint(v);
  dst[e] = (u16)((u + 0x7FFFu + ((u >> 16) & 1u)) >> 16);
}

// ---------------------------------------------------------------------------
// Fused NeRF: 64 rays/block, 4 waves. Single 64x320 swizzled LDS buffer:
//   cols 0..255 = z, cols 256..319 = pe (persists to L4), de overlaid at
//   288..319 after L4. Element (r,c) at u16 addr r*320 + ((c>>3)^(r&7))*8 + (c&7).
// ---------------------------------------------------------------------------
__device__ __forceinline__ void wr_enc(u16* zb, int r, int c, u16 v) {
  zb[r * 320 + ((((c >> 3) ^ (r & 7))) << 3) + (c & 7)] = v;
}

template<int MT_W>
__device__ __forceinline__ void binit(f32x4 acc[MT_W][4],
    const float* __restrict__ bias, int chbase, int lane)
{
  const int q = lane >> 4;
  #pragma unroll
  for (int mt = 0; mt < MT_W; ++mt) {
    float4 bv = *(const float4*)(bias + chbase + mt * 16 + q * 4);
    #pragma unroll
    for (int nt = 0; nt < 4; ++nt)
      acc[mt][nt] = (f32x4){bv.x, bv.y, bv.z, bv.w};
  }
}

// B from swizzled LDS (cbase8 = starting 8-col chunk), A from packed global.
template<int MT_W, int NSTEPS, int MT_TOTAL>
__device__ __forceinline__ void gseg(f32x4 acc[MT_W][4],
    const u16* __restrict__ zb, int cbase8,
    const u16* __restrict__ wl, int mt0, int ksbase, int lane)
{
  const int q = lane >> 4, llo = lane & 15;
  #pragma unroll
  for (int ks = 0; ks < NSTEPS; ++ks) {
    int c8s = ((cbase8 + ks * 4 + q) ^ (llo & 7));
    const u16* bp = zb + llo * 320 + c8s * 8;
    bf16x8 b[4];
    #pragma unroll
    for (int nt = 0; nt < 4; ++nt)
      b[nt] = *(const bf16x8*)(bp + nt * 16 * 320);
    int widx = ((ksbase + ks) * MT_TOTAL + mt0) * 512 + lane * 8;
    bf16x8 a[MT_W];
    #pragma unroll
    for (int mt = 0; mt < MT_W; ++mt)
      a[mt] = *(const bf16x8*)(wl + widx + mt * 512);
    #pragma unroll
    for (int mt = 0; mt < MT_W; ++mt)
      #pragma unroll
      for (int nt = 0; nt < 4; ++nt)
        acc[mt][nt] = __builtin_amdgcn_mfma_f32_16x16x32_bf16(a[mt], b[nt], acc[mt][nt], 0, 0, 0);
  }
}

template<int MT_W, bool RELU>
__device__ __forceinline__ void zstore(f32x4 acc[MT_W][4],
    int chbase, u16* zb, int lane)
{
  const int llo = lane & 15, q = lane >> 4;
  #pragma unroll
  for (int mt = 0; mt < MT_W; ++mt) {
    int ch = chbase + mt * 16 + q * 4;          // 4 consecutive out-channels
    int off0 = (((ch >> 3) ^ (llo & 7)) << 3) + (ch & 7);
    #pragma unroll
    for (int nt = 0; nt < 4; ++nt) {
      f32x4 v = acc[mt][nt];
      float x0 = v.x, x1 = v.y, x2 = v.z, x3 = v.w;
      if (RELU) { x0 = fmaxf(x0, 0.f); x1 = fmaxf(x1, 0.f);
                  x2 = fmaxf(x2, 0.f); x3 = fmaxf(x3, 0.f); }
      u32 a0 = __float_as_uint(x0) + 0x8000u;
      u32 a1 = __float_as_uint(x1) + 0x8000u;
      u32 a2 = __float_as_uint(x2) + 0x8000u;
      u32 a3 = __float_as_uint(x3) + 0x8000u;
      uint2 pk;
      pk.x = (a1 & 0xFFFF0000u) | (a0 >> 16);
      pk.y = (a3 & 0xFFFF0000u) | (a2 >> 16);
      *(uint2*)(zb + (nt * 16 + llo) * 320 + off0) = pk;
    }
  }
}

// launch_bounds(256,3): VGPR budget ~170/lane -> 64 AGPR acc + ~70 arch fits
// with NO scratch spill. (256,4) capped at 128 and spilled ~187 MB/dispatch
// to scratch (R2 post-mortem: WRITE_SIZE 4->187 MB, MfmaUtil 46->35).
__global__ __launch_bounds__(256, 3) void nerf_fused(
    const float* __restrict__ pos,  const float* __restrict__ dirv,
    const float* __restrict__ b00,  const float* __restrict__ b01,
    const float* __restrict__ b02,  const float* __restrict__ b03,
    const float* __restrict__ b10,  const float* __restrict__ b11,
    const float* __restrict__ b12,  const float* __restrict__ b13,
    const float* __restrict__ cb0,  const float* __restrict__ cb1,
    const u16* __restrict__ W, float* __restrict__ out)
{
  __shared__ __align__(16) u16 zb[64 * 320];   // 40960 B
  float* xyzf = (float*)zb;                    // pos scratch in z-region (dead until L0 store)

  const int tid = threadIdx.x;
  const int rb  = blockIdx.x * 64;
  const int lane = tid & 63, wid = tid >> 6;

  if (tid < 192) {
    int r = tid / 3, c = tid - r * 3;
    xyzf[r * 160 + c] = pos[(size_t)(rb + r) * 3 + c];   // byte r*640+4c: no pe overlap
  }
  __syncthreads();

  // pe encode -> zb cols 256..319: [x0..x2, sin(t=j*10+l) t<30, cos, 0]
  #pragma unroll
  for (int i = tid; i < 64 * 32; i += 256) {
    int r = i >> 5, t = i & 31;
    if (t < 30) {
      int j = t / 10, l = t - j * 10;
      float x = xyzf[r * 160 + j] * (float)(1 << l);
      wr_enc(zb, r, 256 + 3 + t,  f2bf(__sinf(x)));
      wr_enc(zb, r, 256 + 33 + t, f2bf(__cosf(x)));
    }
  }
  {
    int r = tid >> 2, c = tid & 3;
    u16 v = 0; int col = 63;
    if (c < 3) { col = c; v = f2bf(xyzf[r * 160 + c]); }
    wr_enc(zb, r, 256 + col, v);
  }
  __syncthreads();

  f32x4 acc[4][4];

  // L0: pe(64) -> 256
  binit<4>(acc, b00, wid * 64, lane);
  gseg<4, 2, 16>(acc, zb, 32, W + PO0, wid * 4, 0, lane);
  __syncthreads();
  zstore<4, true>(acc, wid * 64, zb, lane);
  __syncthreads();
  // L1..L3: 256 -> 256
  binit<4>(acc, b01, wid * 64, lane);
  gseg<4, 8, 16>(acc, zb, 0, W + PO1, wid * 4, 0, lane);
  __syncthreads();
  zstore<4, true>(acc, wid * 64, zb, lane);
  __syncthreads();
  binit<4>(acc, b02, wid * 64, lane);
  gseg<4, 8, 16>(acc, zb, 0, W + PO2, wid * 4, 0, lane);
  __syncthreads();
  zstore<4, true>(acc, wid * 64, zb, lane);
  __syncthreads();
  binit<4>(acc, b03, wid * 64, lane);
  gseg<4, 8, 16>(acc, zb, 0, W + PO3, wid * 4, 0, lane);
  __syncthreads();
  zstore<4, true>(acc, wid * 64, zb, lane);
  __syncthreads();
  // L4: concat(z, pe) 319 -> 256
  binit<4>(acc, b10, wid * 64, lane);
  gseg<4, 8, 16>(acc, zb, 0,  W + PO4, wid * 4, 0, lane);
  gseg<4, 2, 16>(acc, zb, 32, W + PO4, wid * 4, 8, lane);
  __syncthreads();
  zstore<4, true>(acc, wid * 64, zb, lane);
  // de encode -> zb cols 288..319 (pe cols 32..63 dead after L4)
  #pragma unroll
  for (int i = tid; i < 64 * 16; i += 256) {
    int r = i >> 4, t = i & 15;
    if (t < 12) {
      int j = t >> 2, l = t & 3;
      float x = dirv[(size_t)(rb + r) * 3 + j] * (float)(1 << l);
      wr_enc(zb, r, 288 + 3 + t,  f2bf(__sinf(x)));
      wr_enc(zb, r, 288 + 15 + t, f2bf(__cosf(x)));
    } else {
      wr_enc(zb, r, 288 + 15 + t, 0);   // cols 27..30 zero
    }
  }
  {
    int r = tid >> 2, c = tid & 3;
    u16 v = 0; int col = 31;
    if (c < 3) { col = c; v = f2bf(dirv[(size_t)(rb + r) * 3 + c]); }
    wr_enc(zb, r, 288 + col, v);
  }
  __syncthreads();
  // L5, L6: 256 -> 256 relu
  binit<4>(acc, b11, wid * 64, lane);
  gseg<4, 8, 16>(acc, zb, 0, W + PO5, wid * 4, 0, lane);
  __syncthreads();
  zstore<4, true>(acc, wid * 64, zb, lane);
  __syncthreads();
  binit<4>(acc, b12, wid * 64, lane);
  gseg<4, 8, 16>(acc, zb, 0, W + PO6, wid * 4, 0, lane);
  __syncthreads();
  zstore<4, true>(acc, wid * 64, zb, lane);
  __syncthreads();
  // L7: 256 -> 256, NO relu
  binit<4>(acc, b13, wid * 64, lane);
  gseg<4, 8, 16>(acc, zb, 0, W + PO7, wid * 4, 0, lane);
  __syncthreads();
  zstore<4, false>(acc, wid * 64, zb, lane);
  __syncthreads();
  // L8: concat(z, de) 283 -> 128 relu
  {
    f32x4 acc2[2][4];
    binit<2>(acc2, cb0, wid * 32, lane);
    gseg<2, 8, 8>(acc2, zb, 0,  W + PO8, wid * 2, 0, lane);
    gseg<2, 1, 8>(acc2, zb, 36, W + PO8, wid * 2, 8, lane);
    __syncthreads();
    zstore<2, true>(acc2, wid * 32, zb, lane);
    __syncthreads();
  }
  // L9: 128 -> 4 + nonlinearities. One wave handles its 16 rays.
  {
    const u16* W9 = W + PO9;
    const int q = lane >> 4, llo = lane & 15;
    const int r = wid * 16 + llo;
    f32x4 c9 = (f32x4){0.f, 0.f, 0.f, 0.f};
    #pragma unroll
    for (int ks = 0; ks < 4; ++ks) {
      int c8s = ((ks * 4 + q) ^ (llo & 7));
      bf16x8 b = *(const bf16x8*)(zb + r * 320 + c8s * 8);
      bf16x8 a = *(const bf16x8*)(W9 + ks * 512 + lane * 8);
      c9 = __builtin_amdgcn_mfma_f32_16x16x32_bf16(a, b, c9, 0, 0, 0);
    }
    if (q == 0) {
      int ray = rb + r;
      float o0 = c9.x + cb1[0];
      float o1 = c9.y + cb1[1];
      float o2 = c9.z + cb1[2];
      float dv = c9.w + cb1[3];
      out[ray] = (dv > 8.f) ? dv : log1pf(__expf(dv));
      float* rgb = out + NRAYS + (size_t)ray * 3;
      rgb[0] = 1.f / (1.f + __expf(-o0));
      rgb[1] = 1.f / (1.f + __expf(-o1));
      rgb[2] = 1.f / (1.f + __expf(-o2));
    }
  }
}

// ---------------------------------------------------------------------------
extern "C" void kernel_launch(void* const* d_in, const int* in_sizes, int n_in,
                              void* d_out, int out_size, void* d_ws, size_t ws_size,
                              hipStream_t stream)
{
  (void)in_sizes; (void)n_in; (void)out_size; (void)ws_size;
  const float* pos  = (const float*)d_in[0];
  const float* dirv = (const float*)d_in[1];
  PackArgs pa;
  const int widx[10] = {5, 7, 9, 11, 13, 15, 17, 19, 21, 23};
  const int K[10]    = {63, 256, 256, 256, 319, 256, 256, 256, 283, 128};
  const int Nn[10]   = {256, 256, 256, 256, 256, 256, 256, 256, 128, 4};
  const int L2MT[10] = {4, 4, 4, 4, 4, 4, 4, 4, 3, 0};
  const int CS[11]   = {0, 32, 160, 288, 416, 576, 704, 832, 960, 1032, 1036};
  for (int i = 0; i < 10; ++i) {
    pa.src[i] = (const float*)d_in[widx[i]];
    pa.K[i] = K[i]; pa.N[i] = Nn[i]; pa.l2mt[i] = L2MT[i];
  }
  for (int i = 0; i < 11; ++i) pa.cstart[i] = CS[i];

  u16* wp = (u16*)d_ws;
  hipLaunchKernelGGL(pack_w, dim3(TOTAL_PACK_ELEMS / 256), dim3(256), 0, stream, pa, wp);

  hipLaunchKernelGGL(nerf_fused, dim3(NBLK), dim3(256), 0, stream,
      pos, dirv,
      (const float*)d_in[6],  (const float*)d_in[8],
      (const float*)d_in[10], (const float*)d_in[12],
      (const float*)d_in[14], (const float*)d_in[16],
      (const float*)d_in[18], (const float*)d_in[20],
      (const float*)d_in[22], (const float*)d_in[24],
      wp, (float*)d_out);
}